// Round 6
// baseline (336.539 us; speedup 1.0000x reference)
//
#include <hip/hip_runtime.h>
#include <stdint.h>

#define NTOK 2048
#define DIM  1024
#define HID  2048
#define NEXP 8
#define CAP  4224   // 4096 assignments + 128 tile-overflow pad
#define RB   256    // router blocks

typedef __attribute__((ext_vector_type(8))) short short8;
typedef __attribute__((ext_vector_type(4))) float floatx4;
typedef __attribute__((ext_vector_type(4))) unsigned short ushortx4;
typedef __attribute__((ext_vector_type(4))) uint32_t uintx4;

static __device__ __forceinline__ unsigned short f2bf(float f) {
  uint32_t u = __builtin_bit_cast(uint32_t, f);
  u += 0x7fffu + ((u >> 16) & 1u);   // round-to-nearest-even
  return (unsigned short)(u >> 16);
}

// ---------------- router (fp32 exact, no atomics) ----------------
__global__ void __launch_bounds__(256) router_kernel(const float* __restrict__ x,
                                                     const float* __restrict__ Wr,
                                                     int* __restrict__ experts,
                                                     float* __restrict__ wts) {
  const int wave = threadIdx.x >> 6;
  const int lane = threadIdx.x & 63;

#pragma unroll
  for (int j = 0; j < 2; j++) {
    int t = blockIdx.x * 8 + wave * 2 + j;
    const float* xr = x + (size_t)t * DIM;
    float acc[NEXP];
#pragma unroll
    for (int e = 0; e < NEXP; e++) acc[e] = 0.f;
#pragma unroll
    for (int i = 0; i < 4; i++) {
      floatx4 v = ((const floatx4*)xr)[i * 64 + lane];
      int idx = (i * 64 + lane) * 4;
#pragma unroll
      for (int e = 0; e < NEXP; e++) {
        floatx4 w = *(const floatx4*)&Wr[e * DIM + idx];
        acc[e] += v.x * w.x + v.y * w.y + v.z * w.z + v.w * w.w;
      }
    }
#pragma unroll
    for (int e = 0; e < NEXP; e++) {
#pragma unroll
      for (int off = 32; off > 0; off >>= 1) acc[e] += __shfl_down(acc[e], off);
    }
    if (lane == 0) {
      float mx = acc[0];
      for (int e = 1; e < NEXP; e++) mx = fmaxf(mx, acc[e]);
      float p[NEXP], s = 0.f;
      for (int e = 0; e < NEXP; e++) { p[e] = expf(acc[e] - mx); s += p[e]; }
      float inv = 1.f / s;
      for (int e = 0; e < NEXP; e++) p[e] *= inv;
      int i0 = 0; float p0 = p[0];
      for (int e = 1; e < NEXP; e++) if (p[e] > p0) { p0 = p[e]; i0 = e; }   // ties: lowest idx
      int i1 = -1; float p1 = -1.f;
      for (int e = 0; e < NEXP; e++) if (e != i0 && p[e] > p1) { p1 = p[e]; i1 = e; }
      float rn = 1.f / (p0 + p1 + 1e-8f);
      experts[2 * t] = i0; experts[2 * t + 1] = i1;
      wts[2 * t] = p0 * rn; wts[2 * t + 1] = p1 * rn;
    }
  }
}

// ------- scanpos: 8 waves, one expert each; counts, bases, pos[], afor[] -----
__global__ void __launch_bounds__(512) scanpos_kernel(const int* __restrict__ experts,
                                                      int* __restrict__ ctrl,
                                                      int* __restrict__ pos,
                                                      int* __restrict__ afor) {
  const int wv = threadIdx.x >> 6;    // expert owned by this wave
  const int lane = threadIdx.x & 63;
  __shared__ int scnt[NEXP];
  int cnt = 0;
  for (int c = 0; c < 2 * NTOK / 64; c++) {
    int v = experts[c * 64 + lane];
    cnt += __popcll(__ballot(v == wv));
  }
  if (lane == 0) scnt[wv] = cnt;
  __syncthreads();
  int basev = 0;
#pragma unroll
  for (int e = 0; e < NEXP; e++) { int ce = scnt[e]; if (e < wv) basev += ce; }
  if (lane == 0) { ctrl[wv] = cnt; ctrl[8 + wv] = basev; }
  unsigned long long below = (1ull << lane) - 1ull;
  int cur = basev;
  for (int c = 0; c < 2 * NTOK / 64; c++) {
    int a = c * 64 + lane;
    int v = experts[a];
    unsigned long long m = __ballot(v == wv);
    if (v == wv) {
      int p = cur + __popcll(m & below);
      pos[a] = p;
      afor[p] = a;
    }
    cur += __popcll(m);
  }
}

// ---------------- gather: compact token rows into Xe (bf16) ------------------
__global__ void __launch_bounds__(256) gather_kernel(const float* __restrict__ x,
                                                     const int* __restrict__ pos,
                                                     unsigned short* __restrict__ Xe) {
  int t = blockIdx.x;
  int p0 = pos[2 * t], p1 = pos[2 * t + 1];
  int i = threadIdx.x;
  floatx4 v = ((const floatx4*)(x + (size_t)t * DIM))[i];
  ushortx4 b;
  b.x = f2bf(v.x); b.y = f2bf(v.y); b.z = f2bf(v.z); b.w = f2bf(v.w);
  *(ushortx4*)(Xe + (size_t)p0 * DIM + 4 * i) = b;
  *(ushortx4*)(Xe + (size_t)p1 * DIM + 4 * i) = b;
}

// ------------- B-resident expert GEMM: ZERO barriers in the main loop --------
// r1-r5 post-mortem: every per-K-step barrier+vmcnt(0) structure lands at
// 81-96 us (MfmaUtil ~8%, HBM ~18%, VALU ~5% — nothing saturated; the
// issue-drain-stall cycle per step is the bound). Fix: weights (B panel,
// BCOLS x K fp32) are converted ONCE in the prologue into 128 KB of
// XOR-swizzled LDS (granule g^(row&15): 2-way banks = free), then the main
// loop is pure {1 global A-frag load + NSUB ds_read_b128 + NSUB MFMA} per
// 32-k step — no barriers, no waitcnt drains, all iterations independent, so
// loads pipeline deeply. A-frags load DIRECTLY in MFMA layout (lane: row
// l&15, k (l>>4)*8): 16 fully-consumed 64B lines per instr from L2/L3.
// B weights hit HBM exactly once (64 MB = the floor).
// EPI=0: relu(C)^2 -> bf16 He.  EPI=1: fused combine — wts[afor[row]] *
// acc atomicAdd'ed into out (pre-zeroed; 2 adds/element, commutative).
template <int K, int NTOT, int BCOLS, int EPI>
__global__ void __launch_bounds__(512) gemm_kernel(const unsigned short* __restrict__ A,
                                                   const float* __restrict__ B,
                                                   unsigned short* __restrict__ Cbf,
                                                   float* __restrict__ outp,
                                                   const int* __restrict__ ctrl,
                                                   const int* __restrict__ afor,
                                                   const float* __restrict__ wts) {
  const int e = blockIdx.z;
  const int cnt = ctrl[e];
  const int m0 = blockIdx.y * 128;
  if (m0 >= cnt) return;
  const int base = ctrl[8 + e];
  const int n0 = blockIdx.x * BCOLS;

  constexpr int GPR = K / 8;                               // 16B granules per B row
  __shared__ __align__(16) unsigned short ldsB[BCOLS * K]; // 128 KB

  const int tid = threadIdx.x;
  const int lane = tid & 63;
  const int wave = tid >> 6;

  // ---- prologue: B panel fp32 -> bf16 LDS (XOR-swizzled), one barrier ----
  const float* Bp = B + ((size_t)e * NTOT + n0) * (size_t)K;
#pragma unroll 4
  for (int i = 0; i < BCOLS * GPR / 512; i++) {
    int g = i * 512 + tid;
    int row = g / GPR;
    int gc = g % GPR;
    const float* src = Bp + (size_t)row * K + gc * 8;
    floatx4 a = ((const floatx4*)src)[0];
    floatx4 b = ((const floatx4*)src)[1];
    uintx4 uu;
    asm("v_cvt_pk_bf16_f32 %0, %1, %2" : "=v"(uu.x) : "v"(a.x), "v"(a.y));
    asm("v_cvt_pk_bf16_f32 %0, %1, %2" : "=v"(uu.y) : "v"(a.z), "v"(a.w));
    asm("v_cvt_pk_bf16_f32 %0, %1, %2" : "=v"(uu.z) : "v"(b.x), "v"(b.y));
    asm("v_cvt_pk_bf16_f32 %0, %1, %2" : "=v"(uu.w) : "v"(b.z), "v"(b.w));
    int slot = gc ^ (row & 15);
    *(short8*)&ldsB[row * K + slot * 8] = __builtin_bit_cast(short8, uu);
  }
  __syncthreads();   // the ONLY barrier in this kernel

  // ---- main loop: wave owns rows [m0+wave*16, +16) x all BCOLS cols ----
  constexpr int NSUB = BCOLS / 16;
  floatx4 acc[NSUB];
  floatx4 zero = {0.f, 0.f, 0.f, 0.f};
#pragma unroll
  for (int c = 0; c < NSUB; c++) acc[c] = zero;

  const unsigned short* Ap =
      A + ((size_t)(base + m0 + wave * 16 + (lane & 15))) * K + (lane >> 4) * 8;

#pragma unroll 8
  for (int ks = 0; ks < K / 32; ks++) {
    short8 af = *(const short8*)(Ap + ks * 32);
    int gkb = ks * 4 + (lane >> 4);
#pragma unroll
    for (int c = 0; c < NSUB; c++) {
      int brow = c * 16 + (lane & 15);
      short8 bf = *(const short8*)&ldsB[brow * K + (gkb ^ (brow & 15)) * 8];
      acc[c] = __builtin_amdgcn_mfma_f32_16x16x32_bf16(af, bf, acc[c], 0, 0, 0);
    }
  }

  // ---- epilogue: D row=(lane>>4)*4+reg, col=lane&15; mask rows past cnt ----
  const int lm = lane >> 4;
  const int ln = lane & 15;
#pragma unroll
  for (int r = 0; r < 4; r++) {
    int row = m0 + wave * 16 + lm * 4 + r;     // local row in expert segment
    if (row < cnt) {
      if (EPI == 0) {
#pragma unroll
        for (int c = 0; c < NSUB; c++) {
          int col = n0 + c * 16 + ln;
          float v = fmaxf(acc[c][r], 0.f);
          v = v * v;
          Cbf[(size_t)(base + row) * NTOT + col] = f2bf(v);
        }
      } else {
        int a = afor[base + row];
        float w = wts[a];
        size_t tok = (size_t)(a >> 1);
#pragma unroll
        for (int c = 0; c < NSUB; c++) {
          int col = n0 + c * 16 + ln;
          atomicAdd(&outp[tok * DIM + col], w * acc[c][r]);
        }
      }
    }
  }
}

extern "C" void kernel_launch(void* const* d_in, const int* in_sizes, int n_in,
                              void* d_out, int out_size, void* d_ws, size_t ws_size,
                              hipStream_t stream) {
  const float* x   = (const float*)d_in[0];
  const float* Wr  = (const float*)d_in[1];
  const float* Wfc = (const float*)d_in[2];
  const float* Wpr = (const float*)d_in[3];
  float* out = (float*)d_out;
  char* ws = (char*)d_ws;

  int*   ctrl    = (int*)ws;                   // counts[8] bases[8]
  int*   experts = (int*)(ws + 1024);          // int2 per token (16 KB)
  int*   pos     = (int*)(ws + 1024 + 16384);  // int2 per token (16 KB)
  float* wts     = (float*)(ws + 33792);       // float2 per token (16 KB)
  int*   afor    = (int*)(ws + 50176);         // assignment-for-position (CAP ints)
  unsigned short* Xe = (unsigned short*)(ws + 131072);  // [CAP x DIM] bf16
  unsigned short* He = Xe + (size_t)CAP * DIM;          // [CAP x HID] bf16

  hipMemsetAsync(out, 0, out_size, stream);    // fused combine accumulates; also zeroes aux

  router_kernel<<<RB, 256, 0, stream>>>(x, Wr, experts, wts);
  scanpos_kernel<<<1, 512, 0, stream>>>(experts, ctrl, pos, afor);
  gather_kernel<<<NTOK, 256, 0, stream>>>(x, pos, Xe);

  // gemm1: K=1024, 2048 output cols, 64-col panels -> 32 x 16 x 8 blocks
  gemm_kernel<DIM, HID, 64, 0><<<dim3(HID / 64, 16, NEXP), 512, 0, stream>>>(
      Xe, Wfc, He, nullptr, ctrl, nullptr, nullptr);
  // gemm2: K=2048, 1024 output cols, 32-col panels -> 32 x 16 x 8 blocks
  gemm_kernel<HID, DIM, 32, 1><<<dim3(DIM / 32, 16, NEXP), 512, 0, stream>>>(
      He, Wpr, nullptr, out, ctrl, afor, wts);
}

// Round 7
// 300.390 us; speedup vs baseline: 1.1203x; 1.1203x over previous
//
#include <hip/hip_runtime.h>
#include <stdint.h>

#define NTOK 2048
#define DIM  1024
#define HID  2048
#define NEXP 8
#define CAP  4224   // 4096 assignments + 128 tile-overflow pad
#define RB   256    // router blocks

typedef __attribute__((ext_vector_type(8))) short short8;
typedef __attribute__((ext_vector_type(4))) float floatx4;
typedef __attribute__((ext_vector_type(4))) unsigned short ushortx4;
typedef __attribute__((ext_vector_type(4))) uint32_t uintx4;

static __device__ __forceinline__ unsigned short f2bf(float f) {
  uint32_t u = __builtin_bit_cast(uint32_t, f);
  u += 0x7fffu + ((u >> 16) & 1u);   // round-to-nearest-even
  return (unsigned short)(u >> 16);
}

// ---------------- router (fp32 exact, no atomics) ----------------
__global__ void __launch_bounds__(256) router_kernel(const float* __restrict__ x,
                                                     const float* __restrict__ Wr,
                                                     int* __restrict__ experts,
                                                     float* __restrict__ wts) {
  const int wave = threadIdx.x >> 6;
  const int lane = threadIdx.x & 63;

#pragma unroll
  for (int j = 0; j < 2; j++) {
    int t = blockIdx.x * 8 + wave * 2 + j;
    const float* xr = x + (size_t)t * DIM;
    float acc[NEXP];
#pragma unroll
    for (int e = 0; e < NEXP; e++) acc[e] = 0.f;
#pragma unroll
    for (int i = 0; i < 4; i++) {
      floatx4 v = ((const floatx4*)xr)[i * 64 + lane];
      int idx = (i * 64 + lane) * 4;
#pragma unroll
      for (int e = 0; e < NEXP; e++) {
        floatx4 w = *(const floatx4*)&Wr[e * DIM + idx];
        acc[e] += v.x * w.x + v.y * w.y + v.z * w.z + v.w * w.w;
      }
    }
#pragma unroll
    for (int e = 0; e < NEXP; e++) {
#pragma unroll
      for (int off = 32; off > 0; off >>= 1) acc[e] += __shfl_down(acc[e], off);
    }
    if (lane == 0) {
      float mx = acc[0];
      for (int e = 1; e < NEXP; e++) mx = fmaxf(mx, acc[e]);
      float p[NEXP], s = 0.f;
      for (int e = 0; e < NEXP; e++) { p[e] = expf(acc[e] - mx); s += p[e]; }
      float inv = 1.f / s;
      for (int e = 0; e < NEXP; e++) p[e] *= inv;
      int i0 = 0; float p0 = p[0];
      for (int e = 1; e < NEXP; e++) if (p[e] > p0) { p0 = p[e]; i0 = e; }   // ties: lowest idx
      int i1 = -1; float p1 = -1.f;
      for (int e = 0; e < NEXP; e++) if (e != i0 && p[e] > p1) { p1 = p[e]; i1 = e; }
      float rn = 1.f / (p0 + p1 + 1e-8f);
      experts[2 * t] = i0; experts[2 * t + 1] = i1;
      wts[2 * t] = p0 * rn; wts[2 * t + 1] = p1 * rn;
    }
  }
}

// ------- scanpos: 8 waves, one expert each; counts, bases, pos[], afor[] -----
__global__ void __launch_bounds__(512) scanpos_kernel(const int* __restrict__ experts,
                                                      int* __restrict__ ctrl,
                                                      int* __restrict__ pos,
                                                      int* __restrict__ afor) {
  const int wv = threadIdx.x >> 6;    // expert owned by this wave
  const int lane = threadIdx.x & 63;
  __shared__ int scnt[NEXP];
  int cnt = 0;
  for (int c = 0; c < 2 * NTOK / 64; c++) {
    int v = experts[c * 64 + lane];
    cnt += __popcll(__ballot(v == wv));
  }
  if (lane == 0) scnt[wv] = cnt;
  __syncthreads();
  int basev = 0;
#pragma unroll
  for (int e = 0; e < NEXP; e++) { int ce = scnt[e]; if (e < wv) basev += ce; }
  if (lane == 0) { ctrl[wv] = cnt; ctrl[8 + wv] = basev; }
  unsigned long long below = (1ull << lane) - 1ull;
  int cur = basev;
  for (int c = 0; c < 2 * NTOK / 64; c++) {
    int a = c * 64 + lane;
    int v = experts[a];
    unsigned long long m = __ballot(v == wv);
    if (v == wv) {
      int p = cur + __popcll(m & below);
      pos[a] = p;
      afor[p] = a;
    }
    cur += __popcll(m);
  }
}

// ---------------- gather: compact token rows into Xe (bf16) ------------------
__global__ void __launch_bounds__(256) gather_kernel(const float* __restrict__ x,
                                                     const int* __restrict__ pos,
                                                     unsigned short* __restrict__ Xe) {
  int t = blockIdx.x;
  int p0 = pos[2 * t], p1 = pos[2 * t + 1];
  int i = threadIdx.x;
  floatx4 v = ((const floatx4*)(x + (size_t)t * DIM))[i];
  ushortx4 b;
  b.x = f2bf(v.x); b.y = f2bf(v.y); b.z = f2bf(v.z); b.w = f2bf(v.w);
  *(ushortx4*)(Xe + (size_t)p0 * DIM + 4 * i) = b;
  *(ushortx4*)(Xe + (size_t)p1 * DIM + 4 * i) = b;
}

// ---------------- bf16 GEMM (r3 body, measured best: 81 us) ------------------
// + PANEL-LOCALITY XCD SWIZZLE: physical id p -> e = p&7 (one expert per XCD),
//   s = p>>3 with m fastest, n slow. The 16 m-blocks sharing one B panel run
//   back-to-back on ONE XCD; resident window ~6 panels = 3 MB < 4 MB L2, so
//   B re-reads become L2 hits instead of L3/HBM-latency misses (r1-r6: ~1 GB
//   of B re-read flow was the 80 us plateau).
// A: bf16 via global_load_lds (swizzled source, linear dest). B: fp32 weights
// via global_load_lds, cvt to bf16 at ds_read time (v_cvt_pk_bf16_f32, RNE).
// EPI=0: relu(C)^2 -> bf16 He.  EPI=1: FUSED COMBINE — atomicAdd of
// wts[afor[row]] * acc into out (pre-zeroed; 2 commutative adds/element).
template <int K, int N, int EPI>
__global__ void __launch_bounds__(256) gemm_kernel(const unsigned short* __restrict__ A,
                                                   const float* __restrict__ B,
                                                   unsigned short* __restrict__ Cbf,
                                                   float* __restrict__ outp,
                                                   const int* __restrict__ ctrl,
                                                   const int* __restrict__ afor,
                                                   const float* __restrict__ wts) {
  // ---- swizzle: gridDim = (N/128, 16, 8); y (m) is the fast axis per XCD ----
  const int gp = blockIdx.x + gridDim.x * (blockIdx.y + gridDim.y * blockIdx.z);
  const int e = gp & 7;          // XCD-pinned expert
  const int s = gp >> 3;
  const int m_idx = s & 15;      // fast: consecutive blocks share the B panel
  const int n_idx = s >> 4;      // slow: panel switches every 16 blocks

  const int cnt = ctrl[e];
  const int m0 = m_idx * 128;
  if (m0 >= cnt) return;
  const int base = ctrl[8 + e];
  const int n0 = n_idx * 128;

  __shared__ __align__(16) unsigned short ldsA[128 * 64];  // 16 KB bf16
  __shared__ __align__(16) float ldsB[128 * 64];           // 32 KB fp32

  const int tid = threadIdx.x;
  const int lane = tid & 63;
  const int wave = tid >> 6;
  const int wm = wave & 1, wn = wave >> 1;

  const unsigned short* Ae = A + (size_t)(base + m0) * K;
  const float* Be = B + ((size_t)e * N + n0) * (size_t)K;

  // A staging: 4 instrs/wave, 8 rows each; 16B bf16 granules, XOR-swizzled src
  const int rsub = lane >> 3;   // row within 8-row chunk
  const int sg = lane & 7;      // 16B granule slot
  // B staging: 8 instrs/wave, 4 rows each; 32B fp32 granules, XOR-swizzled src
  const int br = lane >> 4;     // row within 4-row chunk
  const int bs = lane & 15;     // 16B slot in row (granule = bs>>1, half = bs&1)

  floatx4 acc[4][4];
  floatx4 zero = {0.f, 0.f, 0.f, 0.f};
#pragma unroll
  for (int i = 0; i < 4; i++)
#pragma unroll
    for (int j = 0; j < 4; j++) acc[i][j] = zero;

  for (int k0 = 0; k0 < K; k0 += 64) {
#pragma unroll
    for (int j = 0; j < 4; j++) {
      int c = wave * 4 + j;
      int rc = c * 8 + rsub;
      int g = sg ^ (rc & 7);
      const unsigned short* ga = Ae + (size_t)rc * K + k0 + g * 8;
      __builtin_amdgcn_global_load_lds((const __attribute__((address_space(1))) unsigned int*)ga,
                                       (__attribute__((address_space(3))) unsigned int*)&ldsA[c * 512],
                                       16, 0, 0);
    }
#pragma unroll
    for (int j = 0; j < 8; j++) {
      int R = wave * 32 + j * 4;            // first row of this instr's 4-row group
      int row = R + br;
      int goff = ((bs >> 1) ^ (row & 7)) * 8 + (bs & 1) * 4;   // swizzled fp32 offset
      const float* gb = Be + (size_t)row * K + k0 + goff;
      __builtin_amdgcn_global_load_lds((const __attribute__((address_space(1))) unsigned int*)gb,
                                       (__attribute__((address_space(3))) unsigned int*)&ldsB[R * 64],
                                       16, 0, 0);
    }
    __builtin_amdgcn_s_waitcnt(0x0f70);  // vmcnt(0)
    __syncthreads();

#pragma unroll
    for (int kk = 0; kk < 2; kk++) {
      int gk = kk * 4 + (lane >> 4);
      short8 af[4], bfr[4];
#pragma unroll
      for (int mi = 0; mi < 4; mi++) {
        int row = wm * 64 + mi * 16 + (lane & 15);
        af[mi] = *(const short8*)&ldsA[row * 64 + (gk ^ (row & 7)) * 8];
      }
#pragma unroll
      for (int ni = 0; ni < 4; ni++) {
        int row = wn * 64 + ni * 16 + (lane & 15);
        const float* pb = &ldsB[row * 64 + (gk ^ (row & 7)) * 8];
        floatx4 x0 = ((const floatx4*)pb)[0];
        floatx4 x1 = ((const floatx4*)pb)[1];
        uintx4 uu;
        asm("v_cvt_pk_bf16_f32 %0, %1, %2" : "=v"(uu.x) : "v"(x0.x), "v"(x0.y));
        asm("v_cvt_pk_bf16_f32 %0, %1, %2" : "=v"(uu.y) : "v"(x0.z), "v"(x0.w));
        asm("v_cvt_pk_bf16_f32 %0, %1, %2" : "=v"(uu.z) : "v"(x1.x), "v"(x1.y));
        asm("v_cvt_pk_bf16_f32 %0, %1, %2" : "=v"(uu.w) : "v"(x1.z), "v"(x1.w));
        bfr[ni] = __builtin_bit_cast(short8, uu);
      }
#pragma unroll
      for (int mi = 0; mi < 4; mi++)
#pragma unroll
        for (int ni = 0; ni < 4; ni++)
          acc[mi][ni] = __builtin_amdgcn_mfma_f32_16x16x32_bf16(af[mi], bfr[ni], acc[mi][ni], 0, 0, 0);
    }
    __syncthreads();
  }

  // epilogue: D row=(lane>>4)*4+reg, col=lane&15; mask stores past cnt.
  const int lm = lane >> 4;
  const int ln = lane & 15;
#pragma unroll
  for (int mi = 0; mi < 4; mi++) {
#pragma unroll
    for (int r = 0; r < 4; r++) {
      int row = m0 + wm * 64 + mi * 16 + lm * 4 + r;   // local row in expert segment
      if (row < cnt) {
        if (EPI == 0) {
#pragma unroll
          for (int ni = 0; ni < 4; ni++) {
            int col = n0 + wn * 64 + ni * 16 + ln;
            float v = fmaxf(acc[mi][ni][r], 0.f);
            v = v * v;
            Cbf[(size_t)(base + row) * N + col] = f2bf(v);
          }
        } else {
          int a = afor[base + row];
          float w = wts[a];
          size_t tok = (size_t)(a >> 1);
#pragma unroll
          for (int ni = 0; ni < 4; ni++) {
            int col = n0 + wn * 64 + ni * 16 + ln;
            atomicAdd(&outp[tok * DIM + col], w * acc[mi][ni][r]);
          }
        }
      }
    }
  }
}

extern "C" void kernel_launch(void* const* d_in, const int* in_sizes, int n_in,
                              void* d_out, int out_size, void* d_ws, size_t ws_size,
                              hipStream_t stream) {
  const float* x   = (const float*)d_in[0];
  const float* Wr  = (const float*)d_in[1];
  const float* Wfc = (const float*)d_in[2];
  const float* Wpr = (const float*)d_in[3];
  float* out = (float*)d_out;
  char* ws = (char*)d_ws;

  int*   ctrl    = (int*)ws;                   // counts[8] bases[8]
  int*   experts = (int*)(ws + 1024);          // int2 per token (16 KB)
  int*   pos     = (int*)(ws + 1024 + 16384);  // int2 per token (16 KB)
  float* wts     = (float*)(ws + 33792);       // float2 per token (16 KB)
  int*   afor    = (int*)(ws + 50176);         // assignment-for-position (CAP ints)
  unsigned short* Xe = (unsigned short*)(ws + 131072);  // [CAP x DIM] bf16
  unsigned short* He = Xe + (size_t)CAP * DIM;          // [CAP x HID] bf16

  hipMemsetAsync(out, 0, out_size, stream);    // fused combine accumulates; zeroes aux too

  router_kernel<<<RB, 256, 0, stream>>>(x, Wr, experts, wts);
  scanpos_kernel<<<1, 512, 0, stream>>>(experts, ctrl, pos, afor);
  gather_kernel<<<NTOK, 256, 0, stream>>>(x, pos, Xe);

  gemm_kernel<DIM, HID, 0><<<dim3(HID / 128, 16, NEXP), 256, 0, stream>>>(
      Xe, Wfc, He, nullptr, ctrl, nullptr, nullptr);
  gemm_kernel<HID, DIM, 1><<<dim3(DIM / 128, 16, NEXP), 256, 0, stream>>>(
      He, Wpr, nullptr, out, ctrl, afor, wts);
}

// Round 8
// 289.028 us; speedup vs baseline: 1.1644x; 1.0393x over previous
//
#include <hip/hip_runtime.h>
#include <stdint.h>

#define NTOK 2048
#define DIM  1024
#define HID  2048
#define NEXP 8
#define CAP  4224   // 4096 assignments + 128 tile-overflow pad
#define RB   256    // router blocks inside fused pre-kernel
#define CBT  8192   // convert blocks per weight tensor (2M granules / 256 thr)

typedef __attribute__((ext_vector_type(8))) short short8;
typedef __attribute__((ext_vector_type(4))) float floatx4;
typedef __attribute__((ext_vector_type(4))) unsigned short ushortx4;
typedef __attribute__((ext_vector_type(8))) unsigned short ushortx8;

static __device__ __forceinline__ unsigned short f2bf(float f) {
  uint32_t u = __builtin_bit_cast(uint32_t, f);
  u += 0x7fffu + ((u >> 16) & 1u);   // round-to-nearest-even
  return (unsigned short)(u >> 16);
}

// ---- fused: router (blocks 0..RB-1) + Wfc fp32->bf16 convert (blocks RB..) --
// r0-proven streaming convert shape (one short chain per thread); only ONE
// tensor now — Wproj's convert is hidden under gemm1 (L2-bound, HBM idle).
__global__ void __launch_bounds__(256) pre_kernel(const float* __restrict__ x,
                                                  const float* __restrict__ Wr,
                                                  const float* __restrict__ Wfc,
                                                  unsigned short* __restrict__ bfc,
                                                  int* __restrict__ experts,
                                                  float* __restrict__ wts) {
  if (blockIdx.x >= RB) {
    size_t idx = (size_t)(blockIdx.x - RB) * 256 + threadIdx.x;
    floatx4 a = ((const floatx4*)Wfc)[2 * idx];
    floatx4 b = ((const floatx4*)Wfc)[2 * idx + 1];
    ushortx8 o;
    o[0] = f2bf(a.x); o[1] = f2bf(a.y); o[2] = f2bf(a.z); o[3] = f2bf(a.w);
    o[4] = f2bf(b.x); o[5] = f2bf(b.y); o[6] = f2bf(b.z); o[7] = f2bf(b.w);
    ((ushortx8*)bfc)[idx] = o;
    return;
  }

  // ---------------- router (fp32 exact, no atomics) ----------------
  const int wave = threadIdx.x >> 6;
  const int lane = threadIdx.x & 63;

#pragma unroll
  for (int j = 0; j < 2; j++) {
    int t = blockIdx.x * 8 + wave * 2 + j;
    const float* xr = x + (size_t)t * DIM;
    float acc[NEXP];
#pragma unroll
    for (int e = 0; e < NEXP; e++) acc[e] = 0.f;
#pragma unroll
    for (int i = 0; i < 4; i++) {
      floatx4 v = ((const floatx4*)xr)[i * 64 + lane];
      int idx = (i * 64 + lane) * 4;
#pragma unroll
      for (int e = 0; e < NEXP; e++) {
        floatx4 w = *(const floatx4*)&Wr[e * DIM + idx];
        acc[e] += v.x * w.x + v.y * w.y + v.z * w.z + v.w * w.w;
      }
    }
#pragma unroll
    for (int e = 0; e < NEXP; e++) {
#pragma unroll
      for (int off = 32; off > 0; off >>= 1) acc[e] += __shfl_down(acc[e], off);
    }
    if (lane == 0) {
      float mx = acc[0];
      for (int e = 1; e < NEXP; e++) mx = fmaxf(mx, acc[e]);
      float p[NEXP], s = 0.f;
      for (int e = 0; e < NEXP; e++) { p[e] = expf(acc[e] - mx); s += p[e]; }
      float inv = 1.f / s;
      for (int e = 0; e < NEXP; e++) p[e] *= inv;
      int i0 = 0; float p0 = p[0];
      for (int e = 1; e < NEXP; e++) if (p[e] > p0) { p0 = p[e]; i0 = e; }   // ties: lowest idx
      int i1 = -1; float p1 = -1.f;
      for (int e = 0; e < NEXP; e++) if (e != i0 && p[e] > p1) { p1 = p[e]; i1 = e; }
      float rn = 1.f / (p0 + p1 + 1e-8f);
      experts[2 * t] = i0; experts[2 * t + 1] = i1;
      wts[2 * t] = p0 * rn; wts[2 * t + 1] = p1 * rn;
    }
  }
}

// ------- scanpos: 8 waves, one expert each; counts, bases, pos[], afor[] -----
__global__ void __launch_bounds__(512) scanpos_kernel(const int* __restrict__ experts,
                                                      int* __restrict__ ctrl,
                                                      int* __restrict__ pos,
                                                      int* __restrict__ afor) {
  const int wv = threadIdx.x >> 6;    // expert owned by this wave
  const int lane = threadIdx.x & 63;
  __shared__ int scnt[NEXP];
  int cnt = 0;
  for (int c = 0; c < 2 * NTOK / 64; c++) {
    int v = experts[c * 64 + lane];
    cnt += __popcll(__ballot(v == wv));
  }
  if (lane == 0) scnt[wv] = cnt;
  __syncthreads();
  int basev = 0;
#pragma unroll
  for (int e = 0; e < NEXP; e++) { int ce = scnt[e]; if (e < wv) basev += ce; }
  if (lane == 0) { ctrl[wv] = cnt; ctrl[8 + wv] = basev; }
  unsigned long long below = (1ull << lane) - 1ull;
  int cur = basev;
  for (int c = 0; c < 2 * NTOK / 64; c++) {
    int a = c * 64 + lane;
    int v = experts[a];
    unsigned long long m = __ballot(v == wv);
    if (v == wv) {
      int p = cur + __popcll(m & below);
      pos[a] = p;
      afor[p] = a;
    }
    cur += __popcll(m);
  }
}

// ---------------- gather: compact token rows into Xe (bf16) ------------------
__global__ void __launch_bounds__(256) gather_kernel(const float* __restrict__ x,
                                                     const int* __restrict__ pos,
                                                     unsigned short* __restrict__ Xe) {
  int t = blockIdx.x;
  int p0 = pos[2 * t], p1 = pos[2 * t + 1];
  int i = threadIdx.x;
  floatx4 v = ((const floatx4*)(x + (size_t)t * DIM))[i];
  ushortx4 b;
  b.x = f2bf(v.x); b.y = f2bf(v.y); b.z = f2bf(v.z); b.w = f2bf(v.w);
  *(ushortx4*)(Xe + (size_t)p0 * DIM + 4 * i) = b;
  *(ushortx4*)(Xe + (size_t)p1 * DIM + 4 * i) = b;
}

// -------- r0's measured-33us bf16 GEMM body (bf16 A AND B via gll) -----------
// r1-r7 lesson: every fp32-B variant pays >=2.5x (per-CU LDS/issue byte
// delivery is the ceiling; fp32 B doubles it). B must be bf16 in LDS.
// CVT=1 (gemm1): blockIdx.y >= 16 are streaming-convert blocks for W_proj
// (HBM-bound) overlapping the L2/LDS-bound GEMM blocks — hides the convert.
// EPI=0: relu(C)^2 -> bf16 He.  EPI=1: fused combine — atomicAdd of
// wts[afor[row]] * acc into pre-zeroed out.
template <int K, int N, int EPI, int CVT>
__global__ void __launch_bounds__(256) gemm_kernel(const unsigned short* __restrict__ A,
                                                   const unsigned short* __restrict__ B,
                                                   unsigned short* __restrict__ Cbf,
                                                   float* __restrict__ outp,
                                                   const int* __restrict__ ctrl,
                                                   const int* __restrict__ afor,
                                                   const float* __restrict__ wts,
                                                   const float* __restrict__ cvt_src,
                                                   unsigned short* __restrict__ cvt_dst) {
  if (CVT && blockIdx.y >= 16) {
    int cb = (blockIdx.y - 16) * (gridDim.x * gridDim.z) + blockIdx.z * gridDim.x + blockIdx.x;
    size_t idx = (size_t)cb * 256 + threadIdx.x;
    floatx4 a = ((const floatx4*)cvt_src)[2 * idx];
    floatx4 b = ((const floatx4*)cvt_src)[2 * idx + 1];
    ushortx8 o;
    o[0] = f2bf(a.x); o[1] = f2bf(a.y); o[2] = f2bf(a.z); o[3] = f2bf(a.w);
    o[4] = f2bf(b.x); o[5] = f2bf(b.y); o[6] = f2bf(b.z); o[7] = f2bf(b.w);
    ((ushortx8*)cvt_dst)[idx] = o;
    return;
  }

  const int e = blockIdx.z;
  const int cnt = ctrl[e];
  const int m0 = blockIdx.y * 128;
  if (m0 >= cnt) return;
  const int base = ctrl[8 + e];
  const int n0 = blockIdx.x * 128;

  __shared__ __align__(16) unsigned short ldsA[128 * 64];
  __shared__ __align__(16) unsigned short ldsB[128 * 64];

  const int tid = threadIdx.x;
  const int lane = tid & 63;
  const int wave = tid >> 6;
  const int wm = wave & 1, wn = wave >> 1;

  const unsigned short* Ae = A + (size_t)(base + m0) * K;
  const unsigned short* Be = B + ((size_t)e * N + n0) * (size_t)K;

  const int rsub = lane >> 3;   // row within 8-row chunk
  const int sg = lane & 7;      // stored 16B group (swizzled)

  floatx4 acc[4][4];
  floatx4 zero = {0.f, 0.f, 0.f, 0.f};
#pragma unroll
  for (int i = 0; i < 4; i++)
#pragma unroll
    for (int j = 0; j < 4; j++) acc[i][j] = zero;

  for (int k0 = 0; k0 < K; k0 += 64) {
#pragma unroll
    for (int j = 0; j < 4; j++) {
      int c = wave * 4 + j;
      int rc = c * 8 + rsub;
      int g = sg ^ (rc & 7);
      const unsigned short* ga = Ae + (size_t)rc * K + k0 + g * 8;
      const unsigned short* gb = Be + (size_t)rc * K + k0 + g * 8;
      __builtin_amdgcn_global_load_lds((const __attribute__((address_space(1))) unsigned int*)ga,
                                       (__attribute__((address_space(3))) unsigned int*)&ldsA[c * 512],
                                       16, 0, 0);
      __builtin_amdgcn_global_load_lds((const __attribute__((address_space(1))) unsigned int*)gb,
                                       (__attribute__((address_space(3))) unsigned int*)&ldsB[c * 512],
                                       16, 0, 0);
    }
    __builtin_amdgcn_s_waitcnt(0x0f70);  // vmcnt(0)
    __syncthreads();

#pragma unroll
    for (int kk = 0; kk < 2; kk++) {
      int q = lane >> 4;
      int gk = kk * 4 + q;
      short8 af[4], bfr[4];
#pragma unroll
      for (int mi = 0; mi < 4; mi++) {
        int row = wm * 64 + mi * 16 + (lane & 15);
        af[mi] = *(const short8*)&ldsA[row * 64 + (gk ^ (row & 7)) * 8];
      }
#pragma unroll
      for (int ni = 0; ni < 4; ni++) {
        int row = wn * 64 + ni * 16 + (lane & 15);
        bfr[ni] = *(const short8*)&ldsB[row * 64 + (gk ^ (row & 7)) * 8];
      }
#pragma unroll
      for (int mi = 0; mi < 4; mi++)
#pragma unroll
        for (int ni = 0; ni < 4; ni++)
          acc[mi][ni] = __builtin_amdgcn_mfma_f32_16x16x32_bf16(af[mi], bfr[ni], acc[mi][ni], 0, 0, 0);
    }
    __syncthreads();
  }

  // epilogue: D row=(lane>>4)*4+reg, col=lane&15; mask stores past cnt.
  const int lm = lane >> 4;
  const int ln = lane & 15;
#pragma unroll
  for (int mi = 0; mi < 4; mi++) {
#pragma unroll
    for (int r = 0; r < 4; r++) {
      int row = m0 + wm * 64 + mi * 16 + lm * 4 + r;   // local row in expert segment
      if (row < cnt) {
        if (EPI == 0) {
#pragma unroll
          for (int ni = 0; ni < 4; ni++) {
            int col = n0 + wn * 64 + ni * 16 + ln;
            float v = fmaxf(acc[mi][ni][r], 0.f);
            v = v * v;
            Cbf[(size_t)(base + row) * N + col] = f2bf(v);
          }
        } else {
          int a = afor[base + row];
          float w = wts[a];
          size_t tok = (size_t)(a >> 1);
#pragma unroll
          for (int ni = 0; ni < 4; ni++) {
            int col = n0 + wn * 64 + ni * 16 + ln;
            atomicAdd(&outp[tok * DIM + col], w * acc[mi][ni][r]);
          }
        }
      }
    }
  }
}

extern "C" void kernel_launch(void* const* d_in, const int* in_sizes, int n_in,
                              void* d_out, int out_size, void* d_ws, size_t ws_size,
                              hipStream_t stream) {
  const float* x   = (const float*)d_in[0];
  const float* Wr  = (const float*)d_in[1];
  const float* Wfc = (const float*)d_in[2];
  const float* Wpr = (const float*)d_in[3];
  float* out = (float*)d_out;
  char* ws = (char*)d_ws;

  const size_t WELEMS = (size_t)NEXP * HID * DIM;  // 16,777,216 per weight tensor

  int*   ctrl    = (int*)ws;                   // counts[8] bases[8]
  int*   experts = (int*)(ws + 1024);          // int2 per token (16 KB)
  int*   pos     = (int*)(ws + 17408);         // int2 per token (16 KB)
  float* wts     = (float*)(ws + 33792);       // float2 per token (16 KB)
  int*   afor    = (int*)(ws + 50176);         // assignment-for-position (CAP ints)
  unsigned short* Wfcb = (unsigned short*)(ws + 131072);
  unsigned short* Wprb = Wfcb + WELEMS;
  unsigned short* Xe   = Wprb + WELEMS;               // [CAP x DIM] bf16
  unsigned short* He   = Xe + (size_t)CAP * DIM;      // [CAP x HID] bf16

  hipMemsetAsync(out, 0, out_size, stream);    // fused combine accumulates; zeroes aux too

  pre_kernel<<<RB + CBT, 256, 0, stream>>>(x, Wr, Wfc, Wfcb, experts, wts);
  scanpos_kernel<<<1, 512, 0, stream>>>(experts, ctrl, pos, afor);
  gather_kernel<<<NTOK, 256, 0, stream>>>(x, pos, Xe);

  // gemm1: y slots [0,16) = GEMM tiles, [16,80) = 8192 W_proj convert blocks
  gemm_kernel<DIM, HID, 0, 1><<<dim3(HID / 128, 80, NEXP), 256, 0, stream>>>(
      Xe, Wfcb, He, nullptr, ctrl, nullptr, nullptr, Wpr, Wprb);
  // gemm2: fused combine (atomicAdd into out)
  gemm_kernel<HID, DIM, 1, 0><<<dim3(DIM / 128, 16, NEXP), 256, 0, stream>>>(
      He, Wprb, nullptr, out, ctrl, afor, wts, nullptr, nullptr);
}